// Round 5
// baseline (85.177 us; speedup 1.0000x reference)
//
#include <hip/hip_runtime.h>
#include <hip/hip_bf16.h>

// Reference = compress(gather nonzeros) -> decompress(scatter back into zeros)
// == identity on x. Output is exactly the f32 input: pure streaming copy.
//
// Round 1: plain float4 grid-stride copy        = 111.0 us (4.85 TB/s combined)
// Round 2: NT loads+stores + strided unroll     = 117.4 us (NT LOADS forced HBM
//          reads every replay — wrong side)
// Round 3: hipMemcpyAsync (runtime tuned blit)  = 110.6 us (parity with R1)
// Round 4: cached loads + NT stores             =  82.8 us (input stays in the
//          256 MiB Infinity Cache across replays; FETCH 256->134 MB profiled)
// Round 5: same cache policy + 4x unrolled independent loads per iteration:
//          deeper MLP to hide L3/HBM read latency under the NT write stream.

typedef float f32x4 __attribute__((ext_vector_type(4)));

__global__ void identity_copy_ntstore_u4(const f32x4* __restrict__ in,
                                         f32x4* __restrict__ out,
                                         long n4) {
    long stride = (long)gridDim.x * blockDim.x;
    long i = (long)blockIdx.x * blockDim.x + threadIdx.x;

    long limit = n4 - 3 * stride;
    for (; i < limit; i += 4 * stride) {
        // 4 independent cached loads in flight, then 4 NT stores
        f32x4 v0 = in[i];
        f32x4 v1 = in[i + stride];
        f32x4 v2 = in[i + 2 * stride];
        f32x4 v3 = in[i + 3 * stride];
        __builtin_nontemporal_store(v0, &out[i]);
        __builtin_nontemporal_store(v1, &out[i + stride]);
        __builtin_nontemporal_store(v2, &out[i + 2 * stride]);
        __builtin_nontemporal_store(v3, &out[i + 3 * stride]);
    }
    for (; i < n4; i += stride) {
        f32x4 v = in[i];
        __builtin_nontemporal_store(v, &out[i]);
    }
}

extern "C" void kernel_launch(void* const* d_in, const int* in_sizes, int n_in,
                              void* d_out, int out_size, void* d_ws, size_t ws_size,
                              hipStream_t stream) {
    const float* x = (const float*)d_in[0];
    float* out = (float*)d_out;
    long n = (long)in_sizes[0];      // 8192*8192 = 67108864, divisible by 4
    long n4 = n / 4;                 // 16777216 float4 elements

    int block = 256;
    int grid = 2048;                 // 8 blocks/CU = 32 waves/CU (full)
    identity_copy_ntstore_u4<<<grid, block, 0, stream>>>(
        (const f32x4*)x, (f32x4*)out, n4);
}